// Round 8
// baseline (399.384 us; speedup 1.0000x reference)
//
#include <hip/hip_runtime.h>
#include <stdint.h>

// ===================== problem constants =====================
constexpr int D_MODEL = 768;
constexpr int SEQ     = 4096;
constexpr int NHEAD   = 12;
constexpr int HDIM    = 64;
constexpr int BATCH   = 2;
constexpr int DFF     = 3072;
constexpr int ROWS    = BATCH * SEQ;   // 8192

typedef __attribute__((ext_vector_type(8))) __bf16 bfrag;
typedef __attribute__((ext_vector_type(8))) short  s16x8;
typedef __attribute__((ext_vector_type(4))) float  f32x4;

#define MFMA16(a, b, c) __builtin_amdgcn_mfma_f32_16x16x32_bf16((a), (b), (c), 0, 0, 0)
#define AS1(p) ((__attribute__((address_space(1))) void*)(uintptr_t)(p))
#define AS3(p) ((__attribute__((address_space(3))) void*)(p))

__device__ __forceinline__ float b2f(short s) {
  union { unsigned u; float f; } c;
  c.u = ((unsigned)(unsigned short)s) << 16;
  return c.f;
}
__device__ __forceinline__ short f2b(float f) {
  union { float f; unsigned u; } c;
  c.f = f;
  unsigned r = c.u + 0x7fffu + ((c.u >> 16) & 1u);  // RNE (finite inputs only)
  return (short)(r >> 16);
}

// ===================== static BigBird plan (constexpr MT19937 == np.random.RandomState(0)) =====================
struct PlanT { int v[64][8]; };

struct MTRng {
  unsigned mt[624];
  int mti;
  constexpr MTRng() : mt{}, mti(624) {
    mt[0] = 0u;
    for (int i = 1; i < 624; ++i)
      mt[i] = 1812433253u * (mt[i-1] ^ (mt[i-1] >> 30)) + (unsigned)i;
  }
  constexpr unsigned next() {
    if (mti >= 624) {
      for (int i = 0; i < 624; ++i) {
        unsigned y = (mt[i] & 0x80000000u) | (mt[(i+1) % 624] & 0x7fffffffu);
        unsigned v = mt[(i+397) % 624] ^ (y >> 1);
        if (y & 1u) v ^= 0x9908b0dfu;
        mt[i] = v;
      }
      mti = 0;
    }
    unsigned y = mt[mti++];
    y ^= y >> 11;
    y ^= (y << 7)  & 0x9d2c5680u;
    y ^= (y << 15) & 0xefc60000u;
    y ^= y >> 18;
    return y;
  }
  constexpr unsigned interval(unsigned mx) {
    unsigned mask = mx;
    mask |= mask >> 1; mask |= mask >> 2; mask |= mask >> 4;
    mask |= mask >> 8; mask |= mask >> 16;
    unsigned v = next() & mask;
    while (v > mx) v = next() & mask;
    return v;
  }
};

constexpr PlanT make_plan() {
  PlanT P{};
  MTRng rng{};
  for (int i = 1; i <= 62; ++i) {
    int cand[64] = {}; int n = 0;
    for (int j = 0; j < 64; ++j) {
      if (j == 0 || j == 63 || j == i-1 || j == i || j == i+1) continue;
      cand[n++] = j;
    }
    int perm[64] = {};
    for (int p = 0; p < n; ++p) perm[p] = p;
    for (int p = n - 1; p > 0; --p) {
      int j = (int)rng.interval((unsigned)p);
      int t = perm[p]; perm[p] = perm[j]; perm[j] = t;
    }
    P.v[i][0] = 0;  P.v[i][1] = 63; P.v[i][2] = i-1; P.v[i][3] = i; P.v[i][4] = i+1;
    P.v[i][5] = cand[perm[0]]; P.v[i][6] = cand[perm[1]]; P.v[i][7] = cand[perm[2]];
  }
  return P;
}
constexpr PlanT h_plan = make_plan();
__constant__ PlanT g_plan = h_plan;

// ===================== layernorm (fp32 in, bf16 out) =====================
__global__ __launch_bounds__(256) void ln_kernel(
    const float* __restrict__ x, const float* __restrict__ sc,
    const float* __restrict__ bi, short* __restrict__ y)
{
  const int row = blockIdx.x, tid = threadIdx.x;
  const size_t base = (size_t)row * D_MODEL;
  float v0 = x[base + tid], v1 = x[base + tid + 256], v2 = x[base + tid + 512];
  float s  = v0 + v1 + v2;
  float s2 = v0*v0 + v1*v1 + v2*v2;
  for (int off = 1; off < 64; off <<= 1) {
    s  += __shfl_xor(s,  off);
    s2 += __shfl_xor(s2, off);
  }
  __shared__ float red[8];
  if ((tid & 63) == 0) { red[tid >> 6] = s; red[4 + (tid >> 6)] = s2; }
  __syncthreads();
  s  = red[0] + red[1] + red[2] + red[3];
  s2 = red[4] + red[5] + red[6] + red[7];
  const float mu  = s * (1.f / 768.f);
  const float var = s2 * (1.f / 768.f) - mu * mu;
  const float rs  = rsqrtf(var + 1e-6f);
  short* yr = y + base;
  yr[tid]       = f2b((v0 - mu) * rs * sc[tid]       + bi[tid]);
  yr[tid + 256] = f2b((v1 - mu) * rs * sc[tid + 256] + bi[tid + 256]);
  yr[tid + 512] = f2b((v2 - mu) * rs * sc[tid + 512] + bi[tid + 512]);
}

// ===================== fused weight transposes (fp32 R x C -> bf16 C x R), 1 dispatch =====================
struct TrArgs { const float* src[6]; short* dst[6]; };

__global__ __launch_bounds__(256) void tr_all(TrArgs a) {
  __shared__ short tile[32][33];
  const int idx = blockIdx.x;
  int w, bx, by, Rr, Cc;
  if (idx < 2304)      { w = idx / 576; int t = idx % 576;  bx = t % 24; by = t / 24; Rr = 768;  Cc = 768;  }
  else if (idx < 4608) { w = 4;         int t = idx - 2304; bx = t % 96; by = t / 96; Rr = 768;  Cc = 3072; }
  else                 { w = 5;         int t = idx - 4608; bx = t % 24; by = t / 24; Rr = 3072; Cc = 768;  }
  const float* in = a.src[w];
  short* out = a.dst[w];
  const int x0 = bx * 32, y0 = by * 32;
  const int tx = threadIdx.x & 31, ty = threadIdx.x >> 5;
  for (int i = 0; i < 32; i += 8)
    tile[ty + i][tx] = f2b(in[(size_t)(y0 + ty + i) * Cc + x0 + tx]);
  __syncthreads();
  for (int i = 0; i < 32; i += 8)
    out[(size_t)(x0 + ty + i) * Rr + y0 + tx] = tile[tx][ty + i];
}

// ===================== GEMM: C[M,N] = A[M,K] @ Bt[N,K]^T, bf16 internal, fp32 acc =====================
// Generalized m97 structure: TM x TN tile, BK, global_load_lds width-16 staging,
// 4 waves in 2x2 layout, each covering (TM/2) x (TN/2).
// Tile sizes chosen per GEMM for BLOCK COUNT (round-7 finding: grid-limited concurrency,
// 4.5 blocks/CU couldn't hide the per-iter vmcnt drain).
enum { M_QKV = 0, M_RES = 3, M_BRELU = 4, M_BRES = 5 };

template <int MODE, int TM, int TN, int BK>
__global__ __launch_bounds__(256, (TM == 128 ? 4 : 6)) void gemm_bt(
    const short* __restrict__ A, const short* __restrict__ Bt,
    void* __restrict__ Cv, short* __restrict__ C2, short* __restrict__ C3,
    const float* __restrict__ res, const float* __restrict__ bias, int N, int K)
{
  constexpr int MT = TM / 32;             // A-frags per wave
  constexpr int NT = TN / 32;             // B-frags per wave
  constexpr int KK = BK / 32;             // MFMA k-steps per tile
  constexpr int AI = TM * BK / 2048;      // global_load_lds instrs per wave (A)
  constexpr int BI = TN * BK / 2048;      // (B)
  alignas(16) __shared__ short As[TM * BK];
  alignas(16) __shared__ short Bs[TN * BK];
  const int tid = threadIdx.x;
  const int wave = tid >> 6, lane = tid & 63;
  const int quad = lane >> 4, l15 = lane & 15;
  const int m0 = blockIdx.x * TM, n0 = blockIdx.y * TN;
  const int mw = (wave & 1) * (TM / 2), nw = (wave >> 1) * (TN / 2);

  f32x4 acc[MT][NT];
#pragma unroll
  for (int i = 0; i < MT; ++i)
#pragma unroll
    for (int j = 0; j < NT; ++j) acc[i][j] = f32x4{0.f, 0.f, 0.f, 0.f};

  // staging: linear LDS fill; lane covers offset wave_chunk + i*512 + lane*8 (elements)
  int arow[AI], acol[AI], brow[BI], bcol[BI];
#pragma unroll
  for (int i = 0; i < AI; ++i) {
    const int off = wave * (TM * BK / 4) + i * 512 + lane * 8;
    arow[i] = off / BK; acol[i] = off % BK;
  }
#pragma unroll
  for (int i = 0; i < BI; ++i) {
    const int off = wave * (TN * BK / 4) + i * 512 + lane * 8;
    brow[i] = off / BK; bcol[i] = off % BK;
  }

  for (int k0 = 0; k0 < K; k0 += BK) {
    __syncthreads();
#pragma unroll
    for (int i = 0; i < AI; ++i)
      __builtin_amdgcn_global_load_lds(AS1(A + (size_t)(m0 + arow[i]) * K + k0 + acol[i]),
                                       AS3(As + wave * (TM * BK / 4) + i * 512), 16, 0, 0);
#pragma unroll
    for (int i = 0; i < BI; ++i)
      __builtin_amdgcn_global_load_lds(AS1(Bt + (size_t)(n0 + brow[i]) * K + k0 + bcol[i]),
                                       AS3(Bs + wave * (TN * BK / 4) + i * 512), 16, 0, 0);
    __syncthreads();
    bfrag af[KK][MT], bfv[KK][NT];
#pragma unroll
    for (int kk = 0; kk < KK; ++kk) {
#pragma unroll
      for (int mt = 0; mt < MT; ++mt)
        af[kk][mt] = *(const bfrag*)(As + (mw + mt*16 + l15) * BK + kk * 32 + quad * 8);
#pragma unroll
      for (int nt = 0; nt < NT; ++nt)
        bfv[kk][nt] = *(const bfrag*)(Bs + (nw + nt*16 + l15) * BK + kk * 32 + quad * 8);
    }
#pragma unroll
    for (int kk = 0; kk < KK; ++kk)
#pragma unroll
      for (int mt = 0; mt < MT; ++mt)
#pragma unroll
        for (int nt = 0; nt < NT; ++nt)
          acc[mt][nt] = MFMA16(af[kk][mt], bfv[kk][nt], acc[mt][nt]);
  }

  // epilogue: C/D layout col = lane&15, row = quad*4 + reg  [m89-verified]
#pragma unroll
  for (int mt = 0; mt < MT; ++mt) {
#pragma unroll
    for (int nt = 0; nt < NT; ++nt) {
#pragma unroll
      for (int r = 0; r < 4; ++r) {
        const int gm = m0 + mw + mt*16 + quad*4 + r;
        const int gn = n0 + nw + nt*16 + l15;
        float v = acc[mt][nt][r];
        if (MODE == M_QKV) {
          const int seg = gn / 768, gn2 = gn - seg * 768;
          if (seg == 0)      ((short*)Cv)[(size_t)gm * 768 + gn2] = f2b(v * 0.125f);
          else if (seg == 1) C2[(size_t)gm * 768 + gn2] = f2b(v);
          else {
            const int bb = gm >> 12, l = gm & 4095, hh = gn2 >> 6, hd = gn2 & 63;
            C3[(((size_t)(bb * NHEAD + hh)) * HDIM + hd) * SEQ + l] = f2b(v);
          }
        } else {
          const size_t ci = (size_t)gm * N + gn;
          if (MODE == M_RES)   { ((float*)Cv)[ci] = v + res[ci]; }
          if (MODE == M_BRELU) { v += bias[gn]; ((short*)Cv)[ci] = f2b(v > 0.f ? v : 0.f); }
          if (MODE == M_BRES)  { ((float*)Cv)[ci] = v + bias[gn] + res[ci]; }
        }
      }
    }
  }
}

// ===================== flash-style BigBird attention =====================
// Block-cooperative K/V LDS staging with one-iteration register prefetch (round-7 win).
constexpr int PSTR = 72;  // P-tile row stride (shorts): b128 reads 2-way max
constexpr int KSTR = 68;  // K/V stage row stride (shorts)

__global__ __launch_bounds__(256, 3) void attn_kernel(
    const short* __restrict__ q, const short* __restrict__ k,
    const short* __restrict__ vt, short* __restrict__ o,
    short* __restrict__ Opart, float* __restrict__ ml)
{
  alignas(16) __shared__ short KV[4][64 * KSTR];        // K0,K1,V0,V1
  alignas(16) __shared__ short Pbuf[4][2 * 16 * PSTR];  // per-wave P
  const int xi = blockIdx.x, h = blockIdx.y, b = blockIdx.z;
  const int tid = threadIdx.x, wave = tid >> 6, lane = tid & 63;
  const int quad = lane >> 4, l15 = lane & 15;
  const int r8 = lane >> 3, g8 = lane & 7;

  int qb, part = 0, g = 0;
  bool partial;
  if (xi < 62) { qb = xi + 1; partial = false; }
  else { const int t = xi - 62; g = t >> 3; part = t & 7; qb = g ? 63 : 0; partial = true; }

  const short* qp = q + (size_t)(b * SEQ + qb * 64 + wave * 16 + l15) * D_MODEL + h * HDIM;
  const bfrag qf0 = *(const bfrag*)(qp + quad * 8);
  const bfrag qf1 = *(const bfrag*)(qp + 32 + quad * 8);

  const short* kb_base = k  + (size_t)b * SEQ * D_MODEL + h * HDIM;
  const short* vt_base = vt + ((size_t)(b * NHEAD + h)) * HDIM * SEQ;

  const int sr0 = wave * 16 + r8, sr1 = wave * 16 + 8 + r8;

  auto kidx = [&](int t, int which) -> int {
    const int tt = t > 3 ? 3 : t;
    return partial ? (part * 8 + 2 * tt + which) : g_plan.v[qb][2 * tt + which];
  };
  auto load8 = [&](int k0i, int k1i, s16x8* R) {
    const short* ka = kb_base + (size_t)k0i * 64 * D_MODEL + g8 * 8;
    const short* kbp = kb_base + (size_t)k1i * 64 * D_MODEL + g8 * 8;
    const short* va = vt_base + (size_t)k0i * 64 + g8 * 8;
    const short* vb = vt_base + (size_t)k1i * 64 + g8 * 8;
    R[0] = *(const s16x8*)(ka  + (size_t)sr0 * D_MODEL);
    R[1] = *(const s16x8*)(ka  + (size_t)sr1 * D_MODEL);
    R[2] = *(const s16x8*)(kbp + (size_t)sr0 * D_MODEL);
    R[3] = *(const s16x8*)(kbp + (size_t)sr1 * D_MODEL);
    R[4] = *(const s16x8*)(va  + (size_t)sr0 * SEQ);
    R[5] = *(const s16x8*)(va  + (size_t)sr1 * SEQ);
    R[6] = *(const s16x8*)(vb  + (size_t)sr0 * SEQ);
    R[7] = *(const s16x8*)(vb  + (size_t)sr1 * SEQ);
  };

  float m_r[4], l_r[4];
  f32x4 oacc[4];
#pragma unroll
  for (int r = 0; r < 4; ++r) { m_r[r] = -1e9f; l_r[r] = 0.f; }
#pragma unroll
  for (int nt = 0; nt < 4; ++nt) oacc[nt] = f32x4{0.f, 0.f, 0.f, 0.f};

  short* pb = &Pbuf[wave][0];

  s16x8 R[8];
  load8(kidx(0, 0), kidx(0, 1), R);

  for (int it = 0; it < 4; ++it) {
    __syncthreads();
#pragma unroll
    for (int bu = 0; bu < 4; ++bu) {
      *(s16x8*)(&KV[bu][sr0 * KSTR + g8 * 8]) = R[2 * bu];
      *(s16x8*)(&KV[bu][sr1 * KSTR + g8 * 8]) = R[2 * bu + 1];
    }
    __syncthreads();

    load8(kidx(it + 1, 0), kidx(it + 1, 1), R);

    // ---- S0, S1 = Q K^T from LDS ----
    f32x4 s0[4], s1[4];
#pragma unroll
    for (int nt = 0; nt < 4; ++nt) {
      const int fr = (nt * 16 + l15) * KSTR + quad * 8;
      const bfrag ka0 = *(const bfrag*)(&KV[0][fr]);
      const bfrag ka1 = *(const bfrag*)(&KV[0][fr + 32]);
      const bfrag kb0 = *(const bfrag*)(&KV[1][fr]);
      const bfrag kb1 = *(const bfrag*)(&KV[1][fr + 32]);
      s0[nt] = f32x4{0.f,0.f,0.f,0.f}; s1[nt] = f32x4{0.f,0.f,0.f,0.f};
      s0[nt] = MFMA16(qf0, ka0, s0[nt]); s0[nt] = MFMA16(qf1, ka1, s0[nt]);
      s1[nt] = MFMA16(qf0, kb0, s1[nt]); s1[nt] = MFMA16(qf1, kb1, s1[nt]);
    }

    // ---- combined online softmax over 128 keys ----
    float alpha[4];
#pragma unroll
    for (int r = 0; r < 4; ++r) {
      float v = fmaxf(fmaxf(fmaxf(s0[0][r], s0[1][r]), fmaxf(s0[2][r], s0[3][r])),
                      fmaxf(fmaxf(s1[0][r], s1[1][r]), fmaxf(s1[2][r], s1[3][r])));
      v = fmaxf(v, __shfl_xor(v, 1));
      v = fmaxf(v, __shfl_xor(v, 2));
      v = fmaxf(v, __shfl_xor(v, 4));
      v = fmaxf(v, __shfl_xor(v, 8));
      const float mn = fmaxf(m_r[r], v);
      alpha[r] = __expf(m_r[r] - mn);
      m_r[r] = mn;
    }
    float psum[4] = {0.f, 0.f, 0.f, 0.f};
#pragma unroll
    for (int nt = 0; nt < 4; ++nt)
#pragma unroll
      for (int r = 0; r < 4; ++r) {
        const float p0 = __expf(s0[nt][r] - m_r[r]);
        const float p1 = __expf(s1[nt][r] - m_r[r]);
        s0[nt][r] = p0; s1[nt][r] = p1;
        psum[r] += p0 + p1;
      }
#pragma unroll
    for (int r = 0; r < 4; ++r) {
      float v = psum[r];
      v += __shfl_xor(v, 1); v += __shfl_xor(v, 2);
      v += __shfl_xor(v, 4); v += __shfl_xor(v, 8);
      l_r[r] = l_r[r] * alpha[r] + v;
    }

    // ---- P0,P1: C-layout -> A-layout via per-wave LDS ----
#pragma unroll
    for (int nt = 0; nt < 4; ++nt)
#pragma unroll
      for (int r = 0; r < 4; ++r) {
        pb[(quad * 4 + r) * PSTR + nt * 16 + l15]             = f2b(s0[nt][r]);
        pb[16 * PSTR + (quad * 4 + r) * PSTR + nt * 16 + l15] = f2b(s1[nt][r]);
      }

    // ---- O = alpha*O + P0 V0 + P1 V1 ----
#pragma unroll
    for (int nt = 0; nt < 4; ++nt)
#pragma unroll
      for (int r = 0; r < 4; ++r) oacc[nt][r] *= alpha[r];
#pragma unroll
    for (int s = 0; s < 2; ++s) {
      const bfrag pf0 = *(const bfrag*)(pb + l15 * PSTR + s * 32 + quad * 8);
      const bfrag pf1 = *(const bfrag*)(pb + 16 * PSTR + l15 * PSTR + s * 32 + quad * 8);
#pragma unroll
      for (int nt = 0; nt < 4; ++nt) {
        const int fr = (nt * 16 + l15) * KSTR + s * 32 + quad * 8;
        const bfrag vf0 = *(const bfrag*)(&KV[2][fr]);
        const bfrag vf1 = *(const bfrag*)(&KV[3][fr]);
        oacc[nt] = MFMA16(pf0, vf0, oacc[nt]);
        oacc[nt] = MFMA16(pf1, vf1, oacc[nt]);
      }
    }
  }

  if (!partial) {
    short* op = o + (size_t)(b * SEQ + qb * 64 + wave * 16) * D_MODEL + h * HDIM;
#pragma unroll
    for (int r = 0; r < 4; ++r) {
      const float inv = 1.f / l_r[r];
#pragma unroll
      for (int nt = 0; nt < 4; ++nt)
        op[(size_t)(quad * 4 + r) * D_MODEL + nt * 16 + l15] = f2b(oacc[nt][r] * inv);
    }
  } else {
    const int pi = ((b * NHEAD + h) * 2 + g) * 8 + part;
    short* Op = Opart + (size_t)pi * 4096;
    float* mp = ml + (size_t)pi * 128;
#pragma unroll
    for (int r = 0; r < 4; ++r) {
      const int row = wave * 16 + quad * 4 + r;
#pragma unroll
      for (int nt = 0; nt < 4; ++nt)
        Op[row * 64 + nt * 16 + l15] = f2b(oacc[nt][r]);
      if (l15 == 0) { mp[row] = m_r[r]; mp[64 + row] = l_r[r]; }
    }
  }
}

// ===================== merge partials for global q-blocks =====================
__global__ __launch_bounds__(256) void attn_merge(
    const short* __restrict__ Opart, const float* __restrict__ ml,
    short* __restrict__ o)
{
  const int bi = blockIdx.x;
  const int g = bi & 1, h = (bi >> 1) % NHEAD, b = bi / (2 * NHEAD);
  const int qb = g ? 63 : 0;
  const int pi0 = bi * 8;
#pragma unroll
  for (int e = 0; e < 16; ++e) {
    const int idx = threadIdx.x + e * 256;
    const int r = idx >> 6, c = idx & 63;
    float ms = -1e9f;
#pragma unroll
    for (int p = 0; p < 8; ++p) ms = fmaxf(ms, ml[(size_t)(pi0 + p) * 128 + r]);
    float lsum = 0.f, osum = 0.f;
#pragma unroll
    for (int p = 0; p < 8; ++p) {
      const float w = __expf(ml[(size_t)(pi0 + p) * 128 + r] - ms);
      lsum += w * ml[(size_t)(pi0 + p) * 128 + 64 + r];
      osum += w * b2f(Opart[(size_t)(pi0 + p) * 4096 + idx]);
    }
    o[(size_t)(b * SEQ + qb * 64 + r) * D_MODEL + h * HDIM + c] = f2b(osum / lsum);
  }
}

// ===================== launch =====================
extern "C" void kernel_launch(void* const* d_in, const int* in_sizes, int n_in,
                              void* d_out, int out_size, void* d_ws, size_t ws_size,
                              hipStream_t stream) {
  (void)in_sizes; (void)n_in; (void)out_size; (void)ws_size;
  const float* x    = (const float*)d_in[0];
  const float* ln1s = (const float*)d_in[1];
  const float* ln1b = (const float*)d_in[2];
  const float* Wq   = (const float*)d_in[3];
  const float* Wk   = (const float*)d_in[4];
  const float* Wv   = (const float*)d_in[5];
  const float* Wo   = (const float*)d_in[6];
  const float* ln2s = (const float*)d_in[7];
  const float* ln2b = (const float*)d_in[8];
  const float* W1   = (const float*)d_in[9];
  const float* b1   = (const float*)d_in[10];
  const float* W2   = (const float*)d_in[11];
  const float* b2   = (const float*)d_in[12];
  float* out = (float*)d_out;

  // ws layout (~77.1 MiB): weightsT (14.2) | hbuf (12.6) | BIG 4x12.6 (tbuf)
  short* WqT  = (short*)((char*)d_ws + 256);
  short* WkT  = WqT  + 768 * 768;          // WqT|WkT|WvT contiguous => fused QKV Bt[2304][768]
  short* WvT  = WkT  + 768 * 768;
  short* WoT  = WvT  + 768 * 768;
  short* W1T  = WoT  + 768 * 768;          // (3072,768)
  short* W2T  = W1T  + (size_t)3072 * 768; // (768,3072)
  short* hbuf = W2T  + (size_t)3072 * 768;
  short* qbuf = hbuf + (size_t)ROWS * D_MODEL;
  short* kbuf = qbuf + (size_t)ROWS * D_MODEL;
  short* vtb  = kbuf + (size_t)ROWS * D_MODEL;
  short* obuf = vtb  + (size_t)ROWS * D_MODEL;
  short* tbuf = qbuf;   // MLP intermediate spans qbuf..obuf (4*ROWS*D_MODEL == ROWS*DFF)
  short* Opart = hbuf;  // attention partials (hbuf dead between QKV GEMM and ln2)
  float* mlbuf = (float*)(hbuf + (size_t)384 * 4096);

  TrArgs ta;
  ta.src[0] = Wq; ta.src[1] = Wk; ta.src[2] = Wv; ta.src[3] = Wo; ta.src[4] = W1; ta.src[5] = W2;
  ta.dst[0] = WqT; ta.dst[1] = WkT; ta.dst[2] = WvT; ta.dst[3] = WoT; ta.dst[4] = W1T; ta.dst[5] = W2T;
  tr_all<<<6912, 256, 0, stream>>>(ta);

  ln_kernel<<<ROWS, 256, 0, stream>>>(x, ln1s, ln1b, hbuf);

  // QKV: 64x128 tile -> 2304 blocks (9/CU)
  gemm_bt<M_QKV, 64, 128, 32><<<dim3(128, 18), 256, 0, stream>>>(hbuf, WqT, qbuf, kbuf, vtb, nullptr, nullptr, 2304, 768);

  attn_kernel<<<dim3(78, 12, 2), 256, 0, stream>>>(qbuf, kbuf, vtb, obuf, Opart, mlbuf);
  attn_merge<<<48, 256, 0, stream>>>(Opart, mlbuf, obuf);

  // Wo+residual: 64x64 tile -> 1536 blocks (6/CU)
  gemm_bt<M_RES, 64, 64, 32><<<dim3(128, 12), 256, 0, stream>>>(obuf, WoT, out, nullptr, nullptr, x, nullptr, 768, 768);

  ln_kernel<<<ROWS, 256, 0, stream>>>(out, ln2s, ln2b, hbuf);

  // MLP1: 64x128 tile -> 3072 blocks (12/CU)
  gemm_bt<M_BRELU, 64, 128, 32><<<dim3(128, 24), 256, 0, stream>>>(hbuf, W1T, tbuf, nullptr, nullptr, nullptr, b1, 3072, 768);
  // MLP2 (K=3072): 128x64 tile, BK=64 (halve serial drains on the deep K loop)
  gemm_bt<M_BRES, 128, 64, 64><<<dim3(64, 12), 256, 0, stream>>>(tbuf, W2T, out, nullptr, nullptr, out, b2, 768, 3072);
}